// Round 12
// baseline (152.146 us; speedup 1.0000x reference)
//
#include <hip/hip_runtime.h>

#define NB 8
#define CH 256
#define CB 128
#define HSW 64
#define HSP (HSW*HSW)   // 4096
#define LW 128
#define LP (LW*LW)      // 16384

typedef __attribute__((ext_vector_type(8))) short bf16x8;
typedef __attribute__((ext_vector_type(4))) float f32x4;

__device__ inline ushort f2bf(float x) {
  uint u = __float_as_uint(x);
  uint r = (u + 0x7fffu + ((u >> 16) & 1u)) >> 16;
  return (ushort)r;
}
__device__ inline float bf2f(uint u) { return __uint_as_float(u << 16); }

__device__ inline bf16x8 ldg8(const ushort* p) {   // 16B load at 8B alignment
  uint2 lo = *(const uint2*)p;
  uint2 hi = *(const uint2*)(p + 4);
  uint4 u = make_uint4(lo.x, lo.y, hi.x, hi.y);
  return *(bf16x8*)&u;
}

// ---- workspace layout (float units) ----
static constexpr size_t S_KVU = (size_t)NB*HSP*CB;       // ushort count (4.2M)

static constexpr size_t OFF_KCM   = 0;                   // k channel-major bf16
static constexpr size_t OFF_VCM   = OFF_KCM + S_KVU/2;   // v channel-major bf16
static constexpr size_t OFF_KM8   = OFF_VCM + S_KVU/2;
static constexpr size_t OFF_KV8T  = OFF_KM8 + (size_t)1800*128;
static constexpr size_t OFF_KM16  = OFF_KV8T + (size_t)1800*4096/2;
static constexpr size_t OFF_KV16T = OFF_KM16 + (size_t)392*128;
static constexpr size_t OFF_WQB   = OFF_KV16T + (size_t)392*4096/2;
static constexpr size_t OFF_WKB   = OFF_WQB + 8192;
static constexpr size_t OFF_WVB   = OFF_WKB + 8192;
static constexpr size_t OFF_WOB   = OFF_WVB + 8192;
static constexpr size_t OFF_CWB   = OFF_WOB + 8192;                   // 32768 ushorts

// ---------------- weight casts to bf16 (wq,wk,wv,wo 128x128; cw 128x256) ----------------
__global__ __launch_bounds__(256)
void k_castw(const float* __restrict__ s0, const float* __restrict__ s1,
             const float* __restrict__ s2, const float* __restrict__ s3,
             const float* __restrict__ s4,
             ushort* __restrict__ d0, ushort* __restrict__ d1,
             ushort* __restrict__ d2, ushort* __restrict__ d3,
             ushort* __restrict__ d4) {
  int y = blockIdx.y;
  const float* s; ushort* d; int n;
  if (y == 0)      { s = s0; d = d0; n = 16384; }
  else if (y == 1) { s = s1; d = d1; n = 16384; }
  else if (y == 2) { s = s2; d = d2; n = 16384; }
  else if (y == 3) { s = s3; d = d3; n = 16384; }
  else             { s = s4; d = d4; n = 32768; }
  int i = (blockIdx.x * 256 + threadIdx.x) * 8;
  if (i >= n) return;
  float4 a = *(const float4*)(s + i);
  float4 b = *(const float4*)(s + i + 4);
  bf16x8 pk;
  pk[0]=(short)f2bf(a.x); pk[1]=(short)f2bf(a.y); pk[2]=(short)f2bf(a.z); pk[3]=(short)f2bf(a.w);
  pk[4]=(short)f2bf(b.x); pk[5]=(short)f2bf(b.y); pk[6]=(short)f2bf(b.z); pk[7]=(short)f2bf(b.w);
  *(bf16x8*)(d + i) = pk;
}

// ---------------- fused conv(MFMA) + LN-stats + LN + k/v projections (MFMA) ----------------
// outputs k/v CHANNEL-MAJOR bf16: kcm[(b*CB + c)*HSP + px]
#define A1S 264
__global__ __launch_bounds__(256)
void k_convkv(const float* __restrict__ high, const ushort* __restrict__ cwb,
              const float* __restrict__ cb, const float* __restrict__ lng,
              const float* __restrict__ lnb,
              const ushort* __restrict__ wkb, const float* __restrict__ bk,
              const ushort* __restrict__ wvb, const float* __restrict__ bv,
              ushort* __restrict__ kcm, ushort* __restrict__ vcm) {
  __shared__ __align__(16) ushort As1[64*A1S];
  __shared__ __align__(16) ushort As2[64*136];
  __shared__ float red[512];
  __shared__ float stat_m[64], stat_r[64];
  int t = threadIdx.x;
  size_t pixbase = (size_t)blockIdx.x * 64;
  int b = blockIdx.x >> 6;                 // 64 blocks per batch
  int prel = (int)(pixbase & (HSP - 1));
  const float* xb = high + (size_t)b*CH*HSP + prel;

  {
    int p = t & 63;
    int cp = (t >> 6) * 2;
    #pragma unroll 4
    for (int pass = 0; pass < 32; ++pass) {
      int c = pass*8 + cp;
      float v0 = xb[(size_t)c*HSP + p];
      float v1 = xb[(size_t)(c+1)*HSP + p];
      uint pk = (uint)f2bf(v0) | ((uint)f2bf(v1) << 16);
      *(uint*)&As1[p*A1S + c] = pk;
    }
  }
  __syncthreads();

  int l = t & 63, h = t >> 6;
  int lr = l & 15, lg = l >> 4;
  int n0 = h * 32;

  f32x4 acc[4][2];
  #pragma unroll
  for (int mt = 0; mt < 4; ++mt)
    #pragma unroll
    for (int nt = 0; nt < 2; ++nt) acc[mt][nt] = (f32x4){0.f,0.f,0.f,0.f};
  #pragma unroll
  for (int k0 = 0; k0 < 256; k0 += 32) {
    bf16x8 a[4], bw[2];
    #pragma unroll
    for (int mt = 0; mt < 4; ++mt)
      a[mt] = *(bf16x8*)&As1[(mt*16+lr)*A1S + k0 + lg*8];
    #pragma unroll
    for (int nt = 0; nt < 2; ++nt)
      bw[nt] = *(const bf16x8*)(cwb + (size_t)(n0 + nt*16 + lr)*256 + k0 + lg*8);
    #pragma unroll
    for (int mt = 0; mt < 4; ++mt)
      #pragma unroll
      for (int nt = 0; nt < 2; ++nt)
        acc[mt][nt] = __builtin_amdgcn_mfma_f32_16x16x32_bf16(a[mt], bw[nt], acc[mt][nt], 0,0,0);
  }
  {
    float cb0 = cb[n0 + lr], cb1 = cb[n0 + 16 + lr];
    #pragma unroll
    for (int mt = 0; mt < 4; ++mt)
      #pragma unroll
      for (int r = 0; r < 4; ++r) { acc[mt][0][r] += cb0; acc[mt][1][r] += cb1; }
  }
  #pragma unroll
  for (int mt = 0; mt < 4; ++mt)
    #pragma unroll
    for (int r = 0; r < 4; ++r) {
      float a0 = acc[mt][0][r], a1 = acc[mt][1][r];
      float s = a0 + a1, ss = a0*a0 + a1*a1;
      #pragma unroll
      for (int off = 1; off < 16; off <<= 1) {
        s  += __shfl_xor(s, off, 64);
        ss += __shfl_xor(ss, off, 64);
      }
      if (lr == 0) {
        int p = mt*16 + lg*4 + r;
        red[h*64 + p] = s;
        red[256 + h*64 + p] = ss;
      }
    }
  __syncthreads();
  if (t < 64) {
    float s  = red[t] + red[64+t] + red[128+t] + red[192+t];
    float ss = red[256+t] + red[320+t] + red[384+t] + red[448+t];
    float m = s * (1.f/128.f);
    float var = ss * (1.f/128.f) - m*m;
    stat_m[t] = m;
    stat_r[t] = rsqrtf(fmaxf(var, 0.f) + 1e-5f);
  }
  __syncthreads();
  {
    float g0 = lng[n0+lr], b0 = lnb[n0+lr];
    float g1 = lng[n0+16+lr], b1 = lnb[n0+16+lr];
    #pragma unroll
    for (int mt = 0; mt < 4; ++mt)
      #pragma unroll
      for (int r = 0; r < 4; ++r) {
        int p = mt*16 + lg*4 + r;
        float m = stat_m[p], rr = stat_r[p];
        As2[p*136 + n0 + lr]      = f2bf((acc[mt][0][r] - m)*rr*g0 + b0);
        As2[p*136 + n0 + 16 + lr] = f2bf((acc[mt][1][r] - m)*rr*g1 + b1);
      }
  }
  __syncthreads();

  f32x4 ak[4][2], av[4][2];
  #pragma unroll
  for (int mt = 0; mt < 4; ++mt)
    #pragma unroll
    for (int nt = 0; nt < 2; ++nt) { ak[mt][nt] = (f32x4){0.f,0.f,0.f,0.f}; av[mt][nt] = (f32x4){0.f,0.f,0.f,0.f}; }
  #pragma unroll
  for (int k0 = 0; k0 < 128; k0 += 32) {
    bf16x8 a[4], bkf[2], bvf[2];
    #pragma unroll
    for (int mt = 0; mt < 4; ++mt)
      a[mt] = *(bf16x8*)&As2[(mt*16+lr)*136 + k0 + lg*8];
    #pragma unroll
    for (int nt = 0; nt < 2; ++nt) {
      bkf[nt] = *(const bf16x8*)(wkb + (size_t)(n0 + nt*16 + lr)*128 + k0 + lg*8);
      bvf[nt] = *(const bf16x8*)(wvb + (size_t)(n0 + nt*16 + lr)*128 + k0 + lg*8);
    }
    #pragma unroll
    for (int mt = 0; mt < 4; ++mt)
      #pragma unroll
      for (int nt = 0; nt < 2; ++nt) {
        ak[mt][nt] = __builtin_amdgcn_mfma_f32_16x16x32_bf16(a[mt], bkf[nt], ak[mt][nt], 0,0,0);
        av[mt][nt] = __builtin_amdgcn_mfma_f32_16x16x32_bf16(a[mt], bvf[nt], av[mt][nt], 0,0,0);
      }
  }
  __syncthreads();
  // k epilogue (bias + elu+1) -> As2
  {
    float bk0 = bk[n0+lr], bk1 = bk[n0+16+lr];
    #pragma unroll
    for (int mt = 0; mt < 4; ++mt)
      #pragma unroll
      for (int r = 0; r < 4; ++r) {
        int p = mt*16 + lg*4 + r;
        float v0 = ak[mt][0][r] + bk0;
        float v1 = ak[mt][1][r] + bk1;
        v0 = (v0 > 0.f) ? v0 + 1.f : __expf(v0);
        v1 = (v1 > 0.f) ? v1 + 1.f : __expf(v1);
        As2[p*136 + n0 + lr]      = f2bf(v0);
        As2[p*136 + n0 + 16 + lr] = f2bf(v1);
      }
  }
  __syncthreads();
  #pragma unroll
  for (int pass = 0; pass < 4; ++pass) {
    int oct = t & 7;
    int c = (t >> 3) + pass*32;
    bf16x8 pk;
    #pragma unroll
    for (int i = 0; i < 8; ++i) pk[i] = (short)As2[(oct*8 + i)*136 + c];
    *(bf16x8*)(kcm + ((size_t)b*CB + c)*HSP + prel + oct*8) = pk;
  }
  __syncthreads();
  // v epilogue (bias, no act) -> As2
  {
    float bv0 = bv[n0+lr], bv1 = bv[n0+16+lr];
    #pragma unroll
    for (int mt = 0; mt < 4; ++mt)
      #pragma unroll
      for (int r = 0; r < 4; ++r) {
        int p = mt*16 + lg*4 + r;
        As2[p*136 + n0 + lr]      = f2bf(av[mt][0][r] + bv0);
        As2[p*136 + n0 + 16 + lr] = f2bf(av[mt][1][r] + bv1);
      }
  }
  __syncthreads();
  #pragma unroll
  for (int pass = 0; pass < 4; ++pass) {
    int oct = t & 7;
    int c = (t >> 3) + pass*32;
    bf16x8 pk;
    #pragma unroll
    for (int i = 0; i < 8; ++i) pk[i] = (short)As2[(oct*8 + i)*136 + c];
    *(bf16x8*)(vcm + ((size_t)b*CB + c)*HSP + prel + oct*8) = pk;
  }
}

// ---------------- MFMA window kv: wave = one window, no LDS ----------------
template<int WS>
__device__ __forceinline__ void win_do(const ushort* __restrict__ kb,
                                       const ushort* __restrict__ vb,
                                       int y0, int x0, int lr, int lg,
                                       float* __restrict__ kmp,
                                       ushort* __restrict__ kvp) {
  constexpr int KS = (WS*WS)/32;
  constexpr float kvscale = 1.f/WS;
  constexpr float kmscale = 1.f/(WS*WS);
  #pragma unroll
  for (int h = 0; h < 4; ++h) {
    f32x4 c00 = {0,0,0,0}, c01 = {0,0,0,0}, c10 = {0,0,0,0}, c11 = {0,0,0,0};
    float sm0 = 0.f, sm1 = 0.f;
    #pragma unroll
    for (int ks = 0; ks < KS; ++ks) {
      int kk = ks*32 + lg*8;
      int yy = kk / WS, xx = kk - (kk/WS)*WS;
      size_t off = (size_t)(y0+yy)*HSW + x0 + xx;
      const ushort* v0p = vb + (size_t)(h*32+lr)*HSP + off;
      const ushort* k0p = kb + (size_t)(h*32+lr)*HSP + off;
      bf16x8 a0 = ldg8(v0p);
      bf16x8 a1 = ldg8(v0p + (size_t)16*HSP);
      bf16x8 b0 = ldg8(k0p);
      bf16x8 b1 = ldg8(k0p + (size_t)16*HSP);
      c00 = __builtin_amdgcn_mfma_f32_16x16x32_bf16(a0, b0, c00, 0,0,0);
      c01 = __builtin_amdgcn_mfma_f32_16x16x32_bf16(a0, b1, c01, 0,0,0);
      c10 = __builtin_amdgcn_mfma_f32_16x16x32_bf16(a1, b0, c10, 0,0,0);
      c11 = __builtin_amdgcn_mfma_f32_16x16x32_bf16(a1, b1, c11, 0,0,0);
      #pragma unroll
      for (int j = 0; j < 8; ++j) {
        sm0 += bf2f((uint)(ushort)b0[j]);
        sm1 += bf2f((uint)(ushort)b1[j]);
      }
    }
    sm0 += __shfl_xor(sm0, 16, 64); sm0 += __shfl_xor(sm0, 32, 64);
    sm1 += __shfl_xor(sm1, 16, 64); sm1 += __shfl_xor(sm1, 32, 64);
    if (lg == 0) {
      kmp[h*32 + lr]      = sm0 * kmscale;
      kmp[h*32 + 16 + lr] = sm1 * kmscale;
    }
    ushort* kh = kvp + h*1024;
    #pragma unroll
    for (int r = 0; r < 4; ++r) {
      kh[(lg*4+r)*32 + lr]           = f2bf(c00[r]*kvscale);
      kh[(lg*4+r)*32 + 16 + lr]      = f2bf(c01[r]*kvscale);
      kh[(16+lg*4+r)*32 + lr]        = f2bf(c10[r]*kvscale);
      kh[(16+lg*4+r)*32 + 16 + lr]   = f2bf(c11[r]*kvscale);
    }
  }
}

__global__ __launch_bounds__(256)
void k_winmfma(const ushort* __restrict__ kcm, const ushort* __restrict__ vcm,
               float* __restrict__ km8, ushort* __restrict__ kv8T,
               float* __restrict__ km16, ushort* __restrict__ kv16T) {
  int t = threadIdx.x;
  int wv = t >> 6, l = t & 63;
  int lr = l & 15, lg = l >> 4;
  int gw = blockIdx.x*4 + wv;
  if (gw < 1800) {
    int b = gw / 225, rem = gw - b*225;
    int wi = rem / 15, wj = rem - (rem/15)*15;
    win_do<8>(kcm + (size_t)b*CB*HSP, vcm + (size_t)b*CB*HSP,
              wi*4, wj*4, lr, lg,
              km8 + (size_t)gw*128, kv8T + (size_t)gw*4096);
  } else {
    int w = gw - 1800;
    int b = w / 49, rem = w - b*49;
    int wi = rem / 7, wj = rem - (rem/7)*7;
    win_do<16>(kcm + (size_t)b*CB*HSP, vcm + (size_t)b*CB*HSP,
               wi*8, wj*8, lr, lg,
               km16 + (size_t)w*128, kv16T + (size_t)w*4096);
  }
}

// ---- fused LN + q-proj + gather-fold + wo-GEMM + blend, per 8x32 tile ----
// 1024 threads = 4 x-quarters x 4 head-waves. Per-quarter logic identical to
// the verified 8x8 pipeline. All global segments are 128B (32px rows).
// smem aliased: ushort As[256][136] <-> float Cs[256][68] <-> LN partials.
__global__ __launch_bounds__(1024)
void k_qfold(const float* __restrict__ low,
             const float* __restrict__ lng, const float* __restrict__ lnb,
             const ushort* __restrict__ wqb, const float* __restrict__ bq,
             const float* __restrict__ km8, const ushort* __restrict__ kv8T,
             const float* __restrict__ km16, const ushort* __restrict__ kv16T,
             const float* __restrict__ wwt,
             const ushort* __restrict__ wobf, const float* __restrict__ bo,
             const float* __restrict__ alpha,
             float* __restrict__ out0, float* __restrict__ out1) {
  __shared__ __align__(16) char smem_raw[256*136*2];   // 69632 B
  ushort* As = (ushort*)smem_raw;
  float* Cs = (float*)smem_raw;                        // [256 oi-rows][68]
  float* redA = (float*)smem_raw;                      // [16 cg][256 px]
  float* redB = redA + 4096;
  __shared__ float stat_m[256], stat_r[256];
  int t = threadIdx.x;
  int hx = t >> 8;            // x-quarter (compute stages)
  int th = t & 255;
  int rbase = hx * 64;
  // XCD swizzle: 512 blocks, 8 XCDs -> each XCD owns one batch image
  int bid = blockIdx.x;
  int swz = (bid & 7) * 64 + (bid >> 3);
  int bb = swz >> 6;
  int tile = swz & 63;
  int y0 = (tile >> 2) * 8;
  int x0t = (tile & 3) * 32;        // tile base x (32 wide)
  int x0 = x0t + hx * 8;            // this quarter's 8x8 sub-tile

  // ---- LN stage: thread owns 4 contiguous x-pixels x 8 channels ----
  int q  = t & 63;            // pixel quad: row = q>>3, xq = q&7
  int cg = t >> 6;            // channel group (8 ch), 0..15
  int row_q = q >> 3, xq = q & 7;
  float4 val[8];
  {
    const float* basep = low + ((size_t)bb*CB + cg*8)*LP + (size_t)(y0+row_q)*LW + x0t + xq*4;
    float s4[4] = {0.f,0.f,0.f,0.f}, ss4[4] = {0.f,0.f,0.f,0.f};
    #pragma unroll
    for (int j = 0; j < 8; ++j) {
      val[j] = *(const float4*)(basep + (size_t)j*LP);
      s4[0] += val[j].x; ss4[0] += val[j].x*val[j].x;
      s4[1] += val[j].y; ss4[1] += val[j].y*val[j].y;
      s4[2] += val[j].z; ss4[2] += val[j].z*val[j].z;
      s4[3] += val[j].w; ss4[3] += val[j].w*val[j].w;
    }
    #pragma unroll
    for (int i = 0; i < 4; ++i) {
      redA[cg*256 + q*4 + i] = s4[i];
      redB[cg*256 + q*4 + i] = ss4[i];
    }
  }
  __syncthreads();
  if (t < 256) {
    float s = 0.f, ss = 0.f;
    #pragma unroll
    for (int g = 0; g < 16; ++g) { s += redA[g*256 + t]; ss += redB[g*256 + t]; }
    float m = s * (1.f/128.f);
    float var = ss * (1.f/128.f) - m*m;
    stat_m[t] = m;                      // tile-linear px: row*32 + x
    stat_r[t] = rsqrtf(fmaxf(var, 0.f) + 1e-5f);
  }
  __syncthreads();
  {
    float g[8], bvls[8];
    #pragma unroll
    for (int j = 0; j < 8; ++j) { g[j] = lng[cg*8+j]; bvls[j] = lnb[cg*8+j]; }
    #pragma unroll
    for (int i = 0; i < 4; ++i) {
      int tp = q*4 + i;
      float m = stat_m[tp], r = stat_r[tp];
      float xv[8];
      #pragma unroll
      for (int j = 0; j < 8; ++j) {
        float xc = (i==0) ? val[j].x : (i==1) ? val[j].y : (i==2) ? val[j].z : val[j].w;
        xv[j] = xc;
      }
      bf16x8 pk;
      #pragma unroll
      for (int j = 0; j < 8; ++j)
        pk[j] = (short)f2bf((xv[j] - m)*r*g[j] + bvls[j]);
      int ar = (xq>>1)*64 + row_q*8 + (xq&1)*4 + i;   // quarter-major pixel order
      *(bf16x8*)&As[ar*136 + cg*8] = pk;
    }
  }
  __syncthreads();

  int l = th & 63, h = th >> 6;
  int lr = l & 15, lg = l >> 4;
  int n0 = h * 32;

  // q-GEMM
  f32x4 qa[4][2];
  #pragma unroll
  for (int mt = 0; mt < 4; ++mt)
    #pragma unroll
    for (int nt = 0; nt < 2; ++nt) qa[mt][nt] = (f32x4){0.f,0.f,0.f,0.f};
  #pragma unroll
  for (int k0 = 0; k0 < 128; k0 += 32) {
    bf16x8 a[4], bf[2];
    #pragma unroll
    for (int mt = 0; mt < 4; ++mt)
      a[mt] = *(bf16x8*)&As[(rbase + mt*16+lr)*136 + k0 + lg*8];
    #pragma unroll
    for (int nt = 0; nt < 2; ++nt)
      bf[nt] = *(const bf16x8*)(wqb + (size_t)(n0 + nt*16 + lr)*128 + k0 + lg*8);
    #pragma unroll
    for (int mt = 0; mt < 4; ++mt)
      #pragma unroll
      for (int nt = 0; nt < 2; ++nt)
        qa[mt][nt] = __builtin_amdgcn_mfma_f32_16x16x32_bf16(a[mt], bf[nt], qa[mt][nt], 0,0,0);
  }
  __syncthreads();
  {
    float b0 = bq[n0+lr], b1 = bq[n0+16+lr];
    #pragma unroll
    for (int mt = 0; mt < 4; ++mt)
      #pragma unroll
      for (int r = 0; r < 4; ++r) {
        int pp = mt*16 + lg*4 + r;
        float v0 = qa[mt][0][r] + b0;
        float v1 = qa[mt][1][r] + b1;
        v0 = (v0 > 0.f) ? v0 + 1.f : __expf(v0);
        v1 = (v1 > 0.f) ? v1 + 1.f : __expf(v1);
        As[(rbase+pp)*136 + n0 + lr]      = f2bf(v0);
        As[(rbase+pp)*136 + n0 + 16 + lr] = f2bf(v1);
      }
  }
  __syncthreads();

  bf16x8 aq[4];
  #pragma unroll
  for (int mt = 0; mt < 4; ++mt)
    aq[mt] = *(bf16x8*)&As[(rbase + mt*16+lr)*136 + h*32 + lg*8];

  float ww0 = wwt[0], ww1 = wwt[1];

  bf16x8 kmf = {0,0,0,0,0,0,0,0};
  {
    int s = lr;
    int wsi = (s >> 2) & 1;
    int n = wsi ? 7 : 15;
    int ar = (y0 >> (3+wsi)) - 1 + ((s>>1)&1);
    int ac = (x0 >> (3+wsi)) - 1 + (s&1);
    if (s < 8 && ar >= 0 && ar < n && ac >= 0 && ac < n) {
      size_t w = ((size_t)bb*n + ar)*n + ac;
      const float* kmp = (wsi ? km16 : km8) + w*(size_t)CB + h*32 + lg*8;
      #pragma unroll
      for (int j = 0; j < 8; ++j) kmf[j] = (short)f2bf(kmp[j]);
    }
  }
  f32x4 z4 = {0.f,0.f,0.f,0.f};
  f32x4 fm[4];
  #pragma unroll
  for (int mt = 0; mt < 4; ++mt) {
    f32x4 zf = __builtin_amdgcn_mfma_f32_16x16x32_bf16(aq[mt], kmf, z4, 0,0,0);
    float wwl = ((lr >> 2) & 1) ? ww1 : ww0;
    #pragma unroll
    for (int r = 0; r < 4; ++r) fm[mt][r] = wwl / (zf[r] + 1e-6f);
  }

  float acc0[4][4], acc1[4][4];
  #pragma unroll
  for (int mt = 0; mt < 4; ++mt)
    #pragma unroll
    for (int r = 0; r < 4; ++r) { acc0[mt][r] = 0.f; acc1[mt][r] = 0.f; }

  #pragma unroll
  for (int s = 0; s < 8; ++s) {
    const int wsi = s >> 2;
    const int n = wsi ? 7 : 15;
    int ar = (y0 >> (3+wsi)) - 1 + ((s>>1)&1);
    int ac = (x0 >> (3+wsi)) - 1 + (s&1);
    if (ar < 0 || ar >= n || ac < 0 || ac >= n) continue;  // wave-uniform
    size_t w = ((size_t)bb*n + ar)*n + ac;
    const ushort* kvp = (wsi ? kv16T : kv8T) + w*4096 + h*1024 + lg*8;
    bf16x8 b0 = *(const bf16x8*)(kvp + (size_t)lr*32);
    bf16x8 b1 = *(const bf16x8*)(kvp + (size_t)(16+lr)*32);
    #pragma unroll
    for (int mt = 0; mt < 4; ++mt) {
      f32x4 pv0 = __builtin_amdgcn_mfma_f32_16x16x32_bf16(aq[mt], b0, z4, 0,0,0);
      f32x4 pv1 = __builtin_amdgcn_mfma_f32_16x16x32_bf16(aq[mt], b1, z4, 0,0,0);
      #pragma unroll
      for (int r = 0; r < 4; ++r) {
        float fv = __shfl(fm[mt][r], (l & 48) | s, 64);
        acc0[mt][r] += fv * pv0[r];
        acc1[mt][r] += fv * pv1[r];
      }
    }
  }
  __syncthreads();
  #pragma unroll
  for (int mt = 0; mt < 4; ++mt)
    #pragma unroll
    for (int r = 0; r < 4; ++r) {
      int pp = mt*16 + lg*4 + r;
      As[(rbase+pp)*136 + n0 + lr]      = f2bf(acc0[mt][r]);
      As[(rbase+pp)*136 + n0 + 16 + lr] = f2bf(acc1[mt][r]);
    }
  __syncthreads();

  // wo-GEMM: C[p][o] = acc @ wo^T
  f32x4 oc[4][2];
  #pragma unroll
  for (int mt = 0; mt < 4; ++mt)
    #pragma unroll
    for (int nt = 0; nt < 2; ++nt) oc[mt][nt] = (f32x4){0.f,0.f,0.f,0.f};
  #pragma unroll
  for (int k0 = 0; k0 < 128; k0 += 32) {
    bf16x8 a[4], bf[2];
    #pragma unroll
    for (int mt = 0; mt < 4; ++mt)
      a[mt] = *(bf16x8*)&As[(rbase + mt*16+lr)*136 + k0 + lg*8];
    #pragma unroll
    for (int nt = 0; nt < 2; ++nt)
      bf[nt] = *(const bf16x8*)(wobf + (size_t)(n0 + nt*16 + lr)*128 + k0 + lg*8);
    #pragma unroll
    for (int mt = 0; mt < 4; ++mt)
      #pragma unroll
      for (int nt = 0; nt < 2; ++nt)
        oc[mt][nt] = __builtin_amdgcn_mfma_f32_16x16x32_bf16(a[mt], bf[nt], oc[mt][nt], 0,0,0);
  }

  // epilogue (full 8x32 tile, 128B segments)
  float aB = alpha[0];
  int xg = t & 7;                 // 4-px x-group within 32-px row
  int row = (t >> 3) & 7;         // tile row
  int oib = t >> 6;               // 0..15
  int xh = xg >> 1;               // quarter of this 4-px group
  int pxl = (xg & 1) * 4;         // px offset within that quarter's 8-px row
  int py_g = y0 + row;
  int cy8  = (py_g >= 8)  + (py_g <= 119);
  int cy16 = (py_g >= 16) + (py_g <= 111);
  float mult[4];
  #pragma unroll
  for (int i = 0; i < 4; ++i) {
    int px_g = x0t + xg*4 + i;
    int cx8  = (px_g >= 8)  + (px_g <= 119);
    int cx16 = (px_g >= 16) + (px_g <= 111);
    mult[i] = (float)(cy8*cx8 + cy16*cx16);
  }
  size_t rowaddr = (size_t)py_g*LW + x0t + xg*4;

  // two passes over o-halves: o = (oi>>4)*32 + nt*16 + (oi&15)
  #pragma unroll
  for (int nt = 0; nt < 2; ++nt) {
    __syncthreads();   // As reads (nt=0) / prior Cs reads (nt=1) done before overwrite
    {
      int oi = h*16 + lr;            // 0..63 within quarter
      #pragma unroll
      for (int mt = 0; mt < 4; ++mt)
        *(f32x4*)&Cs[(rbase + oi)*68 + mt*16 + lg*4] = oc[mt][nt];
    }
    __syncthreads();
    #pragma unroll
    for (int pp = 0; pp < 4; ++pp) {
      int oi = oib + pp*16;                            // 0..63
      int o = ((oi >> 4) << 5) + (nt << 4) + (oi & 15);
      float4 c4 = *(float4*)&Cs[(xh*64 + oi)*68 + row*8 + pxl];
      float bov = bo[o];
      size_t addr = ((size_t)bb*CB + o)*LP + rowaddr;
      float4 lw = *(const float4*)(low + addr);        // L2/L3-hot
      float g0 = 0.5f*(c4.x + bov*mult[0]);
      float g1 = 0.5f*(c4.y + bov*mult[1]);
      float g2 = 0.5f*(c4.z + bov*mult[2]);
      float g3 = 0.5f*(c4.w + bov*mult[3]);
      *(float4*)(out0 + addr) = make_float4(g0,g1,g2,g3);
      *(float4*)(out1 + addr) = make_float4(aB*g0 + (1.f-aB)*lw.x,
                                            aB*g1 + (1.f-aB)*lw.y,
                                            aB*g2 + (1.f-aB)*lw.z,
                                            aB*g3 + (1.f-aB)*lw.w);
    }
  }
}

extern "C" void kernel_launch(void* const* d_in, const int* in_sizes, int n_in,
                              void* d_out, int out_size, void* d_ws, size_t ws_size,
                              hipStream_t stream) {
  const float* high  = (const float*)d_in[0];
  const float* low   = (const float*)d_in[1];
  const float* cw    = (const float*)d_in[2];
  const float* cb    = (const float*)d_in[3];
  const float* lng   = (const float*)d_in[4];
  const float* lnb   = (const float*)d_in[5];
  const float* wq    = (const float*)d_in[6];
  const float* bq    = (const float*)d_in[7];
  const float* wk    = (const float*)d_in[8];
  const float* bk    = (const float*)d_in[9];
  const float* wv    = (const float*)d_in[10];
  const float* bv    = (const float*)d_in[11];
  const float* wo    = (const float*)d_in[12];
  const float* bo    = (const float*)d_in[13];
  const float* wwt   = (const float*)d_in[14];
  const float* alpha = (const float*)d_in[15];

  float* ws   = (float*)d_ws;
  ushort* kcm = (ushort*)(ws + OFF_KCM);
  ushort* vcm = (ushort*)(ws + OFF_VCM);
  float* km8  = ws + OFF_KM8;
  ushort* kv8T  = (ushort*)(ws + OFF_KV8T);
  float* km16 = ws + OFF_KM16;
  ushort* kv16T = (ushort*)(ws + OFF_KV16T);
  ushort* wqb = (ushort*)(ws + OFF_WQB);
  ushort* wkb = (ushort*)(ws + OFF_WKB);
  ushort* wvb = (ushort*)(ws + OFF_WVB);
  ushort* wob = (ushort*)(ws + OFF_WOB);
  ushort* cwb = (ushort*)(ws + OFF_CWB);

  float* out0 = (float*)d_out;
  float* out1 = out0 + (size_t)NB*CB*LP;

  k_castw<<<dim3(16,5), 256, 0, stream>>>(wq, wk, wv, wo, cw, wqb, wkb, wvb, wob, cwb);
  k_convkv<<<512, 256, 0, stream>>>(high, cwb, cb, lng, lnb, wkb, bk, wvb, bv, kcm, vcm);
  k_winmfma<<<548, 256, 0, stream>>>(kcm, vcm, km8, kv8T, km16, kv16T);
  k_qfold<<<512, 1024, 0, stream>>>(low, lng, lnb, wqb, bq, km8, kv8T, km16, kv16T,
                                    wwt, wob, bo, alpha, out0, out1);
}

// Round 13
// 112.948 us; speedup vs baseline: 1.3470x; 1.3470x over previous
//
#include <hip/hip_runtime.h>

#define NB 8
#define CH 256
#define CB 128
#define HSW 64
#define HSP (HSW*HSW)   // 4096
#define LW 128
#define LP (LW*LW)      // 16384

typedef __attribute__((ext_vector_type(8))) short bf16x8;
typedef __attribute__((ext_vector_type(4))) float f32x4;

__device__ inline ushort f2bf(float x) {
  uint u = __float_as_uint(x);
  uint r = (u + 0x7fffu + ((u >> 16) & 1u)) >> 16;
  return (ushort)r;
}
__device__ inline float bf2f(uint u) { return __uint_as_float(u << 16); }

__device__ inline bf16x8 ldg8(const ushort* p) {   // 16B load at 8B alignment
  uint2 lo = *(const uint2*)p;
  uint2 hi = *(const uint2*)(p + 4);
  uint4 u = make_uint4(lo.x, lo.y, hi.x, hi.y);
  return *(bf16x8*)&u;
}

// ---- workspace layout (float units) ----
static constexpr size_t S_KVU = (size_t)NB*HSP*CB;       // ushort count (4.2M)

static constexpr size_t OFF_KCM   = 0;                   // k channel-major bf16
static constexpr size_t OFF_VCM   = OFF_KCM + S_KVU/2;   // v channel-major bf16
static constexpr size_t OFF_KM8   = OFF_VCM + S_KVU/2;
static constexpr size_t OFF_KV8T  = OFF_KM8 + (size_t)1800*128;
static constexpr size_t OFF_KM16  = OFF_KV8T + (size_t)1800*4096/2;
static constexpr size_t OFF_KV16T = OFF_KM16 + (size_t)392*128;
static constexpr size_t OFF_WQB   = OFF_KV16T + (size_t)392*4096/2;
static constexpr size_t OFF_WKB   = OFF_WQB + 8192;
static constexpr size_t OFF_WVB   = OFF_WKB + 8192;
static constexpr size_t OFF_WOB   = OFF_WVB + 8192;
static constexpr size_t OFF_CWB   = OFF_WOB + 8192;                   // 32768 ushorts

// ---------------- weight casts to bf16 (wq,wk,wv,wo 128x128; cw 128x256) ----------------
__global__ __launch_bounds__(256)
void k_castw(const float* __restrict__ s0, const float* __restrict__ s1,
             const float* __restrict__ s2, const float* __restrict__ s3,
             const float* __restrict__ s4,
             ushort* __restrict__ d0, ushort* __restrict__ d1,
             ushort* __restrict__ d2, ushort* __restrict__ d3,
             ushort* __restrict__ d4) {
  int y = blockIdx.y;
  const float* s; ushort* d; int n;
  if (y == 0)      { s = s0; d = d0; n = 16384; }
  else if (y == 1) { s = s1; d = d1; n = 16384; }
  else if (y == 2) { s = s2; d = d2; n = 16384; }
  else if (y == 3) { s = s3; d = d3; n = 16384; }
  else             { s = s4; d = d4; n = 32768; }
  int i = (blockIdx.x * 256 + threadIdx.x) * 8;
  if (i >= n) return;
  float4 a = *(const float4*)(s + i);
  float4 b = *(const float4*)(s + i + 4);
  bf16x8 pk;
  pk[0]=(short)f2bf(a.x); pk[1]=(short)f2bf(a.y); pk[2]=(short)f2bf(a.z); pk[3]=(short)f2bf(a.w);
  pk[4]=(short)f2bf(b.x); pk[5]=(short)f2bf(b.y); pk[6]=(short)f2bf(b.z); pk[7]=(short)f2bf(b.w);
  *(bf16x8*)(d + i) = pk;
}

// ---------------- fused conv(MFMA) + LN-stats + LN + k/v projections (MFMA) ----------------
// outputs k/v CHANNEL-MAJOR bf16: kcm[(b*CB + c)*HSP + px]
#define A1S 264
__global__ __launch_bounds__(256)
void k_convkv(const float* __restrict__ high, const ushort* __restrict__ cwb,
              const float* __restrict__ cb, const float* __restrict__ lng,
              const float* __restrict__ lnb,
              const ushort* __restrict__ wkb, const float* __restrict__ bk,
              const ushort* __restrict__ wvb, const float* __restrict__ bv,
              ushort* __restrict__ kcm, ushort* __restrict__ vcm) {
  __shared__ __align__(16) ushort As1[64*A1S];
  __shared__ __align__(16) ushort As2[64*136];
  __shared__ float red[512];
  __shared__ float stat_m[64], stat_r[64];
  int t = threadIdx.x;
  size_t pixbase = (size_t)blockIdx.x * 64;
  int b = blockIdx.x >> 6;                 // 64 blocks per batch
  int prel = (int)(pixbase & (HSP - 1));
  const float* xb = high + (size_t)b*CH*HSP + prel;

  {
    int p = t & 63;
    int cp = (t >> 6) * 2;
    #pragma unroll 4
    for (int pass = 0; pass < 32; ++pass) {
      int c = pass*8 + cp;
      float v0 = xb[(size_t)c*HSP + p];
      float v1 = xb[(size_t)(c+1)*HSP + p];
      uint pk = (uint)f2bf(v0) | ((uint)f2bf(v1) << 16);
      *(uint*)&As1[p*A1S + c] = pk;
    }
  }
  __syncthreads();

  int l = t & 63, h = t >> 6;
  int lr = l & 15, lg = l >> 4;
  int n0 = h * 32;

  f32x4 acc[4][2];
  #pragma unroll
  for (int mt = 0; mt < 4; ++mt)
    #pragma unroll
    for (int nt = 0; nt < 2; ++nt) acc[mt][nt] = (f32x4){0.f,0.f,0.f,0.f};
  #pragma unroll
  for (int k0 = 0; k0 < 256; k0 += 32) {
    bf16x8 a[4], bw[2];
    #pragma unroll
    for (int mt = 0; mt < 4; ++mt)
      a[mt] = *(bf16x8*)&As1[(mt*16+lr)*A1S + k0 + lg*8];
    #pragma unroll
    for (int nt = 0; nt < 2; ++nt)
      bw[nt] = *(const bf16x8*)(cwb + (size_t)(n0 + nt*16 + lr)*256 + k0 + lg*8);
    #pragma unroll
    for (int mt = 0; mt < 4; ++mt)
      #pragma unroll
      for (int nt = 0; nt < 2; ++nt)
        acc[mt][nt] = __builtin_amdgcn_mfma_f32_16x16x32_bf16(a[mt], bw[nt], acc[mt][nt], 0,0,0);
  }
  {
    float cb0 = cb[n0 + lr], cb1 = cb[n0 + 16 + lr];
    #pragma unroll
    for (int mt = 0; mt < 4; ++mt)
      #pragma unroll
      for (int r = 0; r < 4; ++r) { acc[mt][0][r] += cb0; acc[mt][1][r] += cb1; }
  }
  #pragma unroll
  for (int mt = 0; mt < 4; ++mt)
    #pragma unroll
    for (int r = 0; r < 4; ++r) {
      float a0 = acc[mt][0][r], a1 = acc[mt][1][r];
      float s = a0 + a1, ss = a0*a0 + a1*a1;
      #pragma unroll
      for (int off = 1; off < 16; off <<= 1) {
        s  += __shfl_xor(s, off, 64);
        ss += __shfl_xor(ss, off, 64);
      }
      if (lr == 0) {
        int p = mt*16 + lg*4 + r;
        red[h*64 + p] = s;
        red[256 + h*64 + p] = ss;
      }
    }
  __syncthreads();
  if (t < 64) {
    float s  = red[t] + red[64+t] + red[128+t] + red[192+t];
    float ss = red[256+t] + red[320+t] + red[384+t] + red[448+t];
    float m = s * (1.f/128.f);
    float var = ss * (1.f/128.f) - m*m;
    stat_m[t] = m;
    stat_r[t] = rsqrtf(fmaxf(var, 0.f) + 1e-5f);
  }
  __syncthreads();
  {
    float g0 = lng[n0+lr], b0 = lnb[n0+lr];
    float g1 = lng[n0+16+lr], b1 = lnb[n0+16+lr];
    #pragma unroll
    for (int mt = 0; mt < 4; ++mt)
      #pragma unroll
      for (int r = 0; r < 4; ++r) {
        int p = mt*16 + lg*4 + r;
        float m = stat_m[p], rr = stat_r[p];
        As2[p*136 + n0 + lr]      = f2bf((acc[mt][0][r] - m)*rr*g0 + b0);
        As2[p*136 + n0 + 16 + lr] = f2bf((acc[mt][1][r] - m)*rr*g1 + b1);
      }
  }
  __syncthreads();

  f32x4 ak[4][2], av[4][2];
  #pragma unroll
  for (int mt = 0; mt < 4; ++mt)
    #pragma unroll
    for (int nt = 0; nt < 2; ++nt) { ak[mt][nt] = (f32x4){0.f,0.f,0.f,0.f}; av[mt][nt] = (f32x4){0.f,0.f,0.f,0.f}; }
  #pragma unroll
  for (int k0 = 0; k0 < 128; k0 += 32) {
    bf16x8 a[4], bkf[2], bvf[2];
    #pragma unroll
    for (int mt = 0; mt < 4; ++mt)
      a[mt] = *(bf16x8*)&As2[(mt*16+lr)*136 + k0 + lg*8];
    #pragma unroll
    for (int nt = 0; nt < 2; ++nt) {
      bkf[nt] = *(const bf16x8*)(wkb + (size_t)(n0 + nt*16 + lr)*128 + k0 + lg*8);
      bvf[nt] = *(const bf16x8*)(wvb + (size_t)(n0 + nt*16 + lr)*128 + k0 + lg*8);
    }
    #pragma unroll
    for (int mt = 0; mt < 4; ++mt)
      #pragma unroll
      for (int nt = 0; nt < 2; ++nt) {
        ak[mt][nt] = __builtin_amdgcn_mfma_f32_16x16x32_bf16(a[mt], bkf[nt], ak[mt][nt], 0,0,0);
        av[mt][nt] = __builtin_amdgcn_mfma_f32_16x16x32_bf16(a[mt], bvf[nt], av[mt][nt], 0,0,0);
      }
  }
  __syncthreads();
  // k epilogue (bias + elu+1) -> As2
  {
    float bk0 = bk[n0+lr], bk1 = bk[n0+16+lr];
    #pragma unroll
    for (int mt = 0; mt < 4; ++mt)
      #pragma unroll
      for (int r = 0; r < 4; ++r) {
        int p = mt*16 + lg*4 + r;
        float v0 = ak[mt][0][r] + bk0;
        float v1 = ak[mt][1][r] + bk1;
        v0 = (v0 > 0.f) ? v0 + 1.f : __expf(v0);
        v1 = (v1 > 0.f) ? v1 + 1.f : __expf(v1);
        As2[p*136 + n0 + lr]      = f2bf(v0);
        As2[p*136 + n0 + 16 + lr] = f2bf(v1);
      }
  }
  __syncthreads();
  #pragma unroll
  for (int pass = 0; pass < 4; ++pass) {
    int oct = t & 7;
    int c = (t >> 3) + pass*32;
    bf16x8 pk;
    #pragma unroll
    for (int i = 0; i < 8; ++i) pk[i] = (short)As2[(oct*8 + i)*136 + c];
    *(bf16x8*)(kcm + ((size_t)b*CB + c)*HSP + prel + oct*8) = pk;
  }
  __syncthreads();
  // v epilogue (bias, no act) -> As2
  {
    float bv0 = bv[n0+lr], bv1 = bv[n0+16+lr];
    #pragma unroll
    for (int mt = 0; mt < 4; ++mt)
      #pragma unroll
      for (int r = 0; r < 4; ++r) {
        int p = mt*16 + lg*4 + r;
        As2[p*136 + n0 + lr]      = f2bf(av[mt][0][r] + bv0);
        As2[p*136 + n0 + 16 + lr] = f2bf(av[mt][1][r] + bv1);
      }
  }
  __syncthreads();
  #pragma unroll
  for (int pass = 0; pass < 4; ++pass) {
    int oct = t & 7;
    int c = (t >> 3) + pass*32;
    bf16x8 pk;
    #pragma unroll
    for (int i = 0; i < 8; ++i) pk[i] = (short)As2[(oct*8 + i)*136 + c];
    *(bf16x8*)(vcm + ((size_t)b*CB + c)*HSP + prel + oct*8) = pk;
  }
}

// ---------------- LDS-staged window kv (MFMA) ----------------
// ws8 block (0..479): (b, wi, h) — stages 8-row strip (512 px) x 32 ch of k,v
//   coalesced, computes all 15 windows in the row. gw = b*225 + wi*15 + wj.
// ws16 block (480..703): (b, wi16, h) — two 8-row half-strips, accumulating.
#define WLDS 520   // ushorts per channel row (512 px + 8 pad)
__global__ __launch_bounds__(256)
void k_win2(const ushort* __restrict__ kcm, const ushort* __restrict__ vcm,
            float* __restrict__ km8, ushort* __restrict__ kv8T,
            float* __restrict__ km16, ushort* __restrict__ kv16T) {
  __shared__ __align__(16) ushort kl[32*WLDS];
  __shared__ __align__(16) ushort vl[32*WLDS];
  int t = threadIdx.x;
  int wv = t >> 6, l = t & 63, lr = l & 15, lg = l >> 4;
  int blk = blockIdx.x;
  if (blk < 480) {
    int b = blk / 60, rem = blk - b*60;
    int wi = rem >> 2, h = rem & 3;
    const ushort* kb = kcm + ((size_t)b*CB + h*32)*HSP + wi*4*HSW;
    const ushort* vb = vcm + ((size_t)b*CB + h*32)*HSP + wi*4*HSW;
    #pragma unroll
    for (int it = 0; it < 8; ++it) {
      int e = it*256 + t;
      int c = e >> 6, seg = e & 63;
      *(uint4*)&kl[c*WLDS + seg*8] = *(const uint4*)(kb + (size_t)c*HSP + seg*8);
      *(uint4*)&vl[c*WLDS + seg*8] = *(const uint4*)(vb + (size_t)c*HSP + seg*8);
    }
    __syncthreads();
    for (int wj = wv; wj < 15; wj += 4) {
      int x0 = wj*4;
      f32x4 c00={0,0,0,0}, c01={0,0,0,0}, c10={0,0,0,0}, c11={0,0,0,0};
      float sm0 = 0.f, sm1 = 0.f;
      #pragma unroll
      for (int ks = 0; ks < 2; ++ks) {
        int kk = ks*32 + lg*8;
        int yy = kk >> 3;               // xx = 0 always (kk multiple of 8)
        int lp = yy*HSW + x0;
        bf16x8 a0 = ldg8(&vl[lr*WLDS + lp]);
        bf16x8 a1 = ldg8(&vl[(16+lr)*WLDS + lp]);
        bf16x8 b0 = ldg8(&kl[lr*WLDS + lp]);
        bf16x8 b1 = ldg8(&kl[(16+lr)*WLDS + lp]);
        c00 = __builtin_amdgcn_mfma_f32_16x16x32_bf16(a0, b0, c00, 0,0,0);
        c01 = __builtin_amdgcn_mfma_f32_16x16x32_bf16(a0, b1, c01, 0,0,0);
        c10 = __builtin_amdgcn_mfma_f32_16x16x32_bf16(a1, b0, c10, 0,0,0);
        c11 = __builtin_amdgcn_mfma_f32_16x16x32_bf16(a1, b1, c11, 0,0,0);
        #pragma unroll
        for (int j = 0; j < 8; ++j) {
          sm0 += bf2f((uint)(ushort)b0[j]);
          sm1 += bf2f((uint)(ushort)b1[j]);
        }
      }
      sm0 += __shfl_xor(sm0, 16, 64); sm0 += __shfl_xor(sm0, 32, 64);
      sm1 += __shfl_xor(sm1, 16, 64); sm1 += __shfl_xor(sm1, 32, 64);
      int gw = b*225 + wi*15 + wj;
      if (lg == 0) {
        km8[(size_t)gw*128 + h*32 + lr]      = sm0 * (1.f/64.f);
        km8[(size_t)gw*128 + h*32 + 16 + lr] = sm1 * (1.f/64.f);
      }
      ushort* kh = kv8T + (size_t)gw*4096 + h*1024;
      #pragma unroll
      for (int r = 0; r < 4; ++r) {
        kh[(lg*4+r)*32 + lr]         = f2bf(c00[r]*(1.f/8.f));
        kh[(lg*4+r)*32 + 16 + lr]    = f2bf(c01[r]*(1.f/8.f));
        kh[(16+lg*4+r)*32 + lr]      = f2bf(c10[r]*(1.f/8.f));
        kh[(16+lg*4+r)*32 + 16 + lr] = f2bf(c11[r]*(1.f/8.f));
      }
    }
  } else {
    int bx = blk - 480;
    int b = bx / 28, rem = bx - b*28;
    int wi = rem >> 2, h = rem & 3;          // wi16 0..6
    int y0 = wi*8;
    f32x4 d00[2], d01[2], d10[2], d11[2];
    float s0[2], s1[2];
    #pragma unroll
    for (int w_ = 0; w_ < 2; ++w_) {
      d00[w_] = (f32x4){0,0,0,0}; d01[w_] = (f32x4){0,0,0,0};
      d10[w_] = (f32x4){0,0,0,0}; d11[w_] = (f32x4){0,0,0,0};
      s0[w_] = 0.f; s1[w_] = 0.f;
    }
    for (int yh = 0; yh < 2; ++yh) {
      if (yh) __syncthreads();
      const ushort* kb = kcm + ((size_t)b*CB + h*32)*HSP + (size_t)(y0 + yh*8)*HSW;
      const ushort* vb = vcm + ((size_t)b*CB + h*32)*HSP + (size_t)(y0 + yh*8)*HSW;
      #pragma unroll
      for (int it = 0; it < 8; ++it) {
        int e = it*256 + t;
        int c = e >> 6, seg = e & 63;
        *(uint4*)&kl[c*WLDS + seg*8] = *(const uint4*)(kb + (size_t)c*HSP + seg*8);
        *(uint4*)&vl[c*WLDS + seg*8] = *(const uint4*)(vb + (size_t)c*HSP + seg*8);
      }
      __syncthreads();
      #pragma unroll
      for (int w_ = 0; w_ < 2; ++w_) {
        int wj = wv + w_*4;
        if (wj >= 7) continue;               // wave-uniform
        int x0 = wj*8;
        #pragma unroll
        for (int ks = 0; ks < 4; ++ks) {
          int kk = ks*32 + lg*8;
          int yy = kk >> 4, xx = kk & 15;    // 16-px rows within half-strip
          int lp = yy*HSW + x0 + xx;
          bf16x8 a0 = ldg8(&vl[lr*WLDS + lp]);
          bf16x8 a1 = ldg8(&vl[(16+lr)*WLDS + lp]);
          bf16x8 b0 = ldg8(&kl[lr*WLDS + lp]);
          bf16x8 b1 = ldg8(&kl[(16+lr)*WLDS + lp]);
          d00[w_] = __builtin_amdgcn_mfma_f32_16x16x32_bf16(a0, b0, d00[w_], 0,0,0);
          d01[w_] = __builtin_amdgcn_mfma_f32_16x16x32_bf16(a0, b1, d01[w_], 0,0,0);
          d10[w_] = __builtin_amdgcn_mfma_f32_16x16x32_bf16(a1, b0, d10[w_], 0,0,0);
          d11[w_] = __builtin_amdgcn_mfma_f32_16x16x32_bf16(a1, b1, d11[w_], 0,0,0);
          #pragma unroll
          for (int j = 0; j < 8; ++j) {
            s0[w_] += bf2f((uint)(ushort)b0[j]);
            s1[w_] += bf2f((uint)(ushort)b1[j]);
          }
        }
      }
    }
    #pragma unroll
    for (int w_ = 0; w_ < 2; ++w_) {
      int wj = wv + w_*4;
      if (wj >= 7) continue;
      float sm0 = s0[w_], sm1 = s1[w_];
      sm0 += __shfl_xor(sm0, 16, 64); sm0 += __shfl_xor(sm0, 32, 64);
      sm1 += __shfl_xor(sm1, 16, 64); sm1 += __shfl_xor(sm1, 32, 64);
      int w = b*49 + wi*7 + wj;
      if (lg == 0) {
        km16[(size_t)w*128 + h*32 + lr]      = sm0 * (1.f/256.f);
        km16[(size_t)w*128 + h*32 + 16 + lr] = sm1 * (1.f/256.f);
      }
      ushort* kh = kv16T + (size_t)w*4096 + h*1024;
      #pragma unroll
      for (int r = 0; r < 4; ++r) {
        kh[(lg*4+r)*32 + lr]         = f2bf(d00[w_][r]*(1.f/16.f));
        kh[(lg*4+r)*32 + 16 + lr]    = f2bf(d01[w_][r]*(1.f/16.f));
        kh[(16+lg*4+r)*32 + lr]      = f2bf(d10[w_][r]*(1.f/16.f));
        kh[(16+lg*4+r)*32 + 16 + lr] = f2bf(d11[w_][r]*(1.f/16.f));
      }
    }
  }
}

// ---- fused LN + q-proj + gather-fold + wo-GEMM + blend, per 8x16 tile ----
// (r11 version: 512 threads = 2 x-halves x 4 head-waves; best measured config)
__global__ __launch_bounds__(512)
void k_qfold(const float* __restrict__ low,
             const float* __restrict__ lng, const float* __restrict__ lnb,
             const ushort* __restrict__ wqb, const float* __restrict__ bq,
             const float* __restrict__ km8, const ushort* __restrict__ kv8T,
             const float* __restrict__ km16, const ushort* __restrict__ kv16T,
             const float* __restrict__ wwt,
             const ushort* __restrict__ wobf, const float* __restrict__ bo,
             const float* __restrict__ alpha,
             float* __restrict__ out0, float* __restrict__ out1) {
  __shared__ __align__(16) char smem_raw[128*136*2];   // 34816 B
  ushort* As = (ushort*)smem_raw;
  float* Cs = (float*)smem_raw;                        // [128 oi-rows][68]
  float* redA = (float*)smem_raw;                      // [16 cg][128 px]
  float* redB = redA + 2048;
  __shared__ float stat_m[128], stat_r[128];
  int t = threadIdx.x;
  int hx = t >> 8;            // x-half (compute stages)
  int th = t & 255;
  int rbase = hx * 64;
  int bid = blockIdx.x;
  int swz = (bid & 7) * 128 + (bid >> 3);
  int bb = swz >> 7;
  int tile = swz & 127;
  int y0 = (tile >> 3) * 8;
  int x0t = (tile & 7) * 16;
  int x0 = x0t + hx * 8;

  // ---- LN stage: thread owns 4 contiguous x-pixels x 8 channels ----
  int q  = t & 31;
  int cg = t >> 5;
  int row_q = q >> 2, xq = q & 3;
  float4 val[8];
  {
    const float* basep = low + ((size_t)bb*CB + cg*8)*LP + (size_t)(y0+row_q)*LW + x0t + xq*4;
    float s4[4] = {0.f,0.f,0.f,0.f}, ss4[4] = {0.f,0.f,0.f,0.f};
    #pragma unroll
    for (int j = 0; j < 8; ++j) {
      val[j] = *(const float4*)(basep + (size_t)j*LP);
      s4[0] += val[j].x; ss4[0] += val[j].x*val[j].x;
      s4[1] += val[j].y; ss4[1] += val[j].y*val[j].y;
      s4[2] += val[j].z; ss4[2] += val[j].z*val[j].z;
      s4[3] += val[j].w; ss4[3] += val[j].w*val[j].w;
    }
    #pragma unroll
    for (int i = 0; i < 4; ++i) {
      redA[cg*128 + q*4 + i] = s4[i];
      redB[cg*128 + q*4 + i] = ss4[i];
    }
  }
  __syncthreads();
  if (t < 128) {
    float s = 0.f, ss = 0.f;
    #pragma unroll
    for (int g = 0; g < 16; ++g) { s += redA[g*128 + t]; ss += redB[g*128 + t]; }
    float m = s * (1.f/128.f);
    float var = ss * (1.f/128.f) - m*m;
    stat_m[t] = m;
    stat_r[t] = rsqrtf(fmaxf(var, 0.f) + 1e-5f);
  }
  __syncthreads();
  {
    float g[8], bvls[8];
    #pragma unroll
    for (int j = 0; j < 8; ++j) { g[j] = lng[cg*8+j]; bvls[j] = lnb[cg*8+j]; }
    #pragma unroll
    for (int i = 0; i < 4; ++i) {
      int tp = q*4 + i;
      float m = stat_m[tp], r = stat_r[tp];
      float xv[8];
      #pragma unroll
      for (int j = 0; j < 8; ++j) {
        float xc = (i==0) ? val[j].x : (i==1) ? val[j].y : (i==2) ? val[j].z : val[j].w;
        xv[j] = xc;
      }
      bf16x8 pk;
      #pragma unroll
      for (int j = 0; j < 8; ++j)
        pk[j] = (short)f2bf((xv[j] - m)*r*g[j] + bvls[j]);
      int ar = (xq>>1)*64 + row_q*8 + (xq&1)*4 + i;
      *(bf16x8*)&As[ar*136 + cg*8] = pk;
    }
  }
  __syncthreads();

  int l = th & 63, h = th >> 6;
  int lr = l & 15, lg = l >> 4;
  int n0 = h * 32;

  // q-GEMM
  f32x4 qa[4][2];
  #pragma unroll
  for (int mt = 0; mt < 4; ++mt)
    #pragma unroll
    for (int nt = 0; nt < 2; ++nt) qa[mt][nt] = (f32x4){0.f,0.f,0.f,0.f};
  #pragma unroll
  for (int k0 = 0; k0 < 128; k0 += 32) {
    bf16x8 a[4], bf[2];
    #pragma unroll
    for (int mt = 0; mt < 4; ++mt)
      a[mt] = *(bf16x8*)&As[(rbase + mt*16+lr)*136 + k0 + lg*8];
    #pragma unroll
    for (int nt = 0; nt < 2; ++nt)
      bf[nt] = *(const bf16x8*)(wqb + (size_t)(n0 + nt*16 + lr)*128 + k0 + lg*8);
    #pragma unroll
    for (int mt = 0; mt < 4; ++mt)
      #pragma unroll
      for (int nt = 0; nt < 2; ++nt)
        qa[mt][nt] = __builtin_amdgcn_mfma_f32_16x16x32_bf16(a[mt], bf[nt], qa[mt][nt], 0,0,0);
  }
  __syncthreads();
  {
    float b0 = bq[n0+lr], b1 = bq[n0+16+lr];
    #pragma unroll
    for (int mt = 0; mt < 4; ++mt)
      #pragma unroll
      for (int r = 0; r < 4; ++r) {
        int pp = mt*16 + lg*4 + r;
        float v0 = qa[mt][0][r] + b0;
        float v1 = qa[mt][1][r] + b1;
        v0 = (v0 > 0.f) ? v0 + 1.f : __expf(v0);
        v1 = (v1 > 0.f) ? v1 + 1.f : __expf(v1);
        As[(rbase+pp)*136 + n0 + lr]      = f2bf(v0);
        As[(rbase+pp)*136 + n0 + 16 + lr] = f2bf(v1);
      }
  }
  __syncthreads();

  bf16x8 aq[4];
  #pragma unroll
  for (int mt = 0; mt < 4; ++mt)
    aq[mt] = *(bf16x8*)&As[(rbase + mt*16+lr)*136 + h*32 + lg*8];

  float ww0 = wwt[0], ww1 = wwt[1];

  bf16x8 kmf = {0,0,0,0,0,0,0,0};
  {
    int s = lr;
    int wsi = (s >> 2) & 1;
    int n = wsi ? 7 : 15;
    int ar = (y0 >> (3+wsi)) - 1 + ((s>>1)&1);
    int ac = (x0 >> (3+wsi)) - 1 + (s&1);
    if (s < 8 && ar >= 0 && ar < n && ac >= 0 && ac < n) {
      size_t w = ((size_t)bb*n + ar)*n + ac;
      const float* kmp = (wsi ? km16 : km8) + w*(size_t)CB + h*32 + lg*8;
      #pragma unroll
      for (int j = 0; j < 8; ++j) kmf[j] = (short)f2bf(kmp[j]);
    }
  }
  f32x4 z4 = {0.f,0.f,0.f,0.f};
  f32x4 fm[4];
  #pragma unroll
  for (int mt = 0; mt < 4; ++mt) {
    f32x4 zf = __builtin_amdgcn_mfma_f32_16x16x32_bf16(aq[mt], kmf, z4, 0,0,0);
    float wwl = ((lr >> 2) & 1) ? ww1 : ww0;
    #pragma unroll
    for (int r = 0; r < 4; ++r) fm[mt][r] = wwl / (zf[r] + 1e-6f);
  }

  float acc0[4][4], acc1[4][4];
  #pragma unroll
  for (int mt = 0; mt < 4; ++mt)
    #pragma unroll
    for (int r = 0; r < 4; ++r) { acc0[mt][r] = 0.f; acc1[mt][r] = 0.f; }

  #pragma unroll
  for (int s = 0; s < 8; ++s) {
    const int wsi = s >> 2;
    const int n = wsi ? 7 : 15;
    int ar = (y0 >> (3+wsi)) - 1 + ((s>>1)&1);
    int ac = (x0 >> (3+wsi)) - 1 + (s&1);
    if (ar < 0 || ar >= n || ac < 0 || ac >= n) continue;  // wave-uniform
    size_t w = ((size_t)bb*n + ar)*n + ac;
    const ushort* kvp = (wsi ? kv16T : kv8T) + w*4096 + h*1024 + lg*8;
    bf16x8 b0 = *(const bf16x8*)(kvp + (size_t)lr*32);
    bf16x8 b1 = *(const bf16x8*)(kvp + (size_t)(16+lr)*32);
    #pragma unroll
    for (int mt = 0; mt < 4; ++mt) {
      f32x4 pv0 = __builtin_amdgcn_mfma_f32_16x16x32_bf16(aq[mt], b0, z4, 0,0,0);
      f32x4 pv1 = __builtin_amdgcn_mfma_f32_16x16x32_bf16(aq[mt], b1, z4, 0,0,0);
      #pragma unroll
      for (int r = 0; r < 4; ++r) {
        float fv = __shfl(fm[mt][r], (l & 48) | s, 64);
        acc0[mt][r] += fv * pv0[r];
        acc1[mt][r] += fv * pv1[r];
      }
    }
  }
  __syncthreads();
  #pragma unroll
  for (int mt = 0; mt < 4; ++mt)
    #pragma unroll
    for (int r = 0; r < 4; ++r) {
      int pp = mt*16 + lg*4 + r;
      As[(rbase+pp)*136 + n0 + lr]      = f2bf(acc0[mt][r]);
      As[(rbase+pp)*136 + n0 + 16 + lr] = f2bf(acc1[mt][r]);
    }
  __syncthreads();

  // wo-GEMM: C[p][o] = acc @ wo^T
  f32x4 oc[4][2];
  #pragma unroll
  for (int mt = 0; mt < 4; ++mt)
    #pragma unroll
    for (int nt = 0; nt < 2; ++nt) oc[mt][nt] = (f32x4){0.f,0.f,0.f,0.f};
  #pragma unroll
  for (int k0 = 0; k0 < 128; k0 += 32) {
    bf16x8 a[4], bf[2];
    #pragma unroll
    for (int mt = 0; mt < 4; ++mt)
      a[mt] = *(bf16x8*)&As[(rbase + mt*16+lr)*136 + k0 + lg*8];
    #pragma unroll
    for (int nt = 0; nt < 2; ++nt)
      bf[nt] = *(const bf16x8*)(wobf + (size_t)(n0 + nt*16 + lr)*128 + k0 + lg*8);
    #pragma unroll
    for (int mt = 0; mt < 4; ++mt)
      #pragma unroll
      for (int nt = 0; nt < 2; ++nt)
        oc[mt][nt] = __builtin_amdgcn_mfma_f32_16x16x32_bf16(a[mt], bf[nt], oc[mt][nt], 0,0,0);
  }

  float aB = alpha[0];
  int xg = t & 3;
  int row = (t >> 2) & 7;
  int oib = t >> 5;
  int xh = xg >> 1;
  int pxl = (xg & 1) * 4;
  int py_g = y0 + row;
  int cy8  = (py_g >= 8)  + (py_g <= 119);
  int cy16 = (py_g >= 16) + (py_g <= 111);
  float mult[4];
  #pragma unroll
  for (int i = 0; i < 4; ++i) {
    int px_g = x0t + xg*4 + i;
    int cx8  = (px_g >= 8)  + (px_g <= 119);
    int cx16 = (px_g >= 16) + (px_g <= 111);
    mult[i] = (float)(cy8*cx8 + cy16*cx16);
  }
  size_t rowaddr = (size_t)py_g*LW + x0t + xg*4;

  #pragma unroll
  for (int nt = 0; nt < 2; ++nt) {
    __syncthreads();
    {
      int oi = h*16 + lr;
      #pragma unroll
      for (int mt = 0; mt < 4; ++mt)
        *(f32x4*)&Cs[(rbase + oi)*68 + mt*16 + lg*4] = oc[mt][nt];
    }
    __syncthreads();
    #pragma unroll
    for (int pp = 0; pp < 4; ++pp) {
      int oi = oib + pp*16;
      int o = ((oi >> 4) << 5) + (nt << 4) + (oi & 15);
      float4 c4 = *(float4*)&Cs[(xh*64 + oi)*68 + row*8 + pxl];
      float bov = bo[o];
      size_t addr = ((size_t)bb*CB + o)*LP + rowaddr;
      float4 lw = *(const float4*)(low + addr);
      float g0 = 0.5f*(c4.x + bov*mult[0]);
      float g1 = 0.5f*(c4.y + bov*mult[1]);
      float g2 = 0.5f*(c4.z + bov*mult[2]);
      float g3 = 0.5f*(c4.w + bov*mult[3]);
      *(float4*)(out0 + addr) = make_float4(g0,g1,g2,g3);
      *(float4*)(out1 + addr) = make_float4(aB*g0 + (1.f-aB)*lw.x,
                                            aB*g1 + (1.f-aB)*lw.y,
                                            aB*g2 + (1.f-aB)*lw.z,
                                            aB*g3 + (1.f-aB)*lw.w);
    }
  }
}

extern "C" void kernel_launch(void* const* d_in, const int* in_sizes, int n_in,
                              void* d_out, int out_size, void* d_ws, size_t ws_size,
                              hipStream_t stream) {
  const float* high  = (const float*)d_in[0];
  const float* low   = (const float*)d_in[1];
  const float* cw    = (const float*)d_in[2];
  const float* cb    = (const float*)d_in[3];
  const float* lng   = (const float*)d_in[4];
  const float* lnb   = (const float*)d_in[5];
  const float* wq    = (const float*)d_in[6];
  const float* bq    = (const float*)d_in[7];
  const float* wk    = (const float*)d_in[8];
  const float* bk    = (const float*)d_in[9];
  const float* wv    = (const float*)d_in[10];
  const float* bv    = (const float*)d_in[11];
  const float* wo    = (const float*)d_in[12];
  const float* bo    = (const float*)d_in[13];
  const float* wwt   = (const float*)d_in[14];
  const float* alpha = (const float*)d_in[15];

  float* ws   = (float*)d_ws;
  ushort* kcm = (ushort*)(ws + OFF_KCM);
  ushort* vcm = (ushort*)(ws + OFF_VCM);
  float* km8  = ws + OFF_KM8;
  ushort* kv8T  = (ushort*)(ws + OFF_KV8T);
  float* km16 = ws + OFF_KM16;
  ushort* kv16T = (ushort*)(ws + OFF_KV16T);
  ushort* wqb = (ushort*)(ws + OFF_WQB);
  ushort* wkb = (ushort*)(ws + OFF_WKB);
  ushort* wvb = (ushort*)(ws + OFF_WVB);
  ushort* wob = (ushort*)(ws + OFF_WOB);
  ushort* cwb = (ushort*)(ws + OFF_CWB);

  float* out0 = (float*)d_out;
  float* out1 = out0 + (size_t)NB*CB*LP;

  k_castw<<<dim3(16,5), 256, 0, stream>>>(wq, wk, wv, wo, cw, wqb, wkb, wvb, wob, cwb);
  k_convkv<<<512, 256, 0, stream>>>(high, cwb, cb, lng, lnb, wkb, bk, wvb, bv, kcm, vcm);
  k_win2<<<704, 256, 0, stream>>>(kcm, vcm, km8, kv8T, km16, kv16T);
  k_qfold<<<1024, 512, 0, stream>>>(low, lng, lnb, wqb, bq, km8, kv8T, km16, kv16T,
                                    wwt, wob, bo, alpha, out0, out1);
}